// Round 14
// baseline (593.894 us; speedup 1.0000x reference)
//
#include <hip/hip_runtime.h>
#include <hip/hip_bf16.h>
#include <math.h>

#define N_NODES 50000
#define N_EDGES 800000
#define IN_F 256
#define G 128                    // 2*HID
#define NHID 64
#define NGRAPH 32
#define NBUCK ((N_NODES + 255) / 256)    // 196 buckets (dst>>8)
#define CAPB 8192                         // srcs capacity per bucket (mean 4352+256)
#define CELL 64                           // pairs capacity per (bucket, binA-block)
#define POOL_NODES 64
#define EPB 4096                          // edges per binA block
#define NBA ((N_EDGES + EPB - 1) / EPB)   // 196 (real edges only; self-loops direct)

typedef __hip_bfloat16 bf16;
typedef unsigned short ushort;
typedef __attribute__((ext_vector_type(8))) short short8;
typedef __attribute__((ext_vector_type(4))) float f32x4;

// ---------- dtype-agnostic loads ----------
__device__ __forceinline__ float bf2f(ushort u) {
    union { unsigned u; float f; } c; c.u = ((unsigned)u) << 16; return c.f;
}
// round-to-nearest-even f32 -> bf16 (finite inputs)
__device__ __forceinline__ ushort f2bf(float f) {
    unsigned u = __float_as_uint(f);
    u += 0x7FFFu + ((u >> 16) & 1u);
    return (ushort)(u >> 16);
}
__device__ __forceinline__ float ldf(const void* p, long i, int f32) {
    return f32 ? ((const float*)p)[i] : bf2f(((const ushort*)p)[i]);
}
__device__ __forceinline__ int ldi(const void* p, long i, int i64) {
    return i64 ? (int)((const long long*)p)[i] : ((const int*)p)[i];
}

__device__ __forceinline__ float selu_f(float x) {
    const float sc = 1.0507009873554805f, al = 1.6732632423543772f;
    return x > 0.f ? sc * x : sc * al * expm1f(x);
}

// async global->LDS, 16 B/lane; lds base must be wave-uniform.
typedef const __attribute__((address_space(1))) void gas_void;
typedef __attribute__((address_space(3))) void las_void;
__device__ __forceinline__ void stage16(const void* g, void* l) {
    __builtin_amdgcn_global_load_lds((gas_void*)g, (las_void*)l, 16, 0, 0);
}

__device__ __forceinline__ void edge_sd(const void* __restrict__ ei, int e, int i64,
                                        int& s, int& d) {
    s = ldi(ei, e, i64);
    d = ldi(ei, (long)N_EDGES + e, i64);
    s = min(max(s, 0), N_NODES - 1);
    d = min(max(d, 0), N_NODES - 1);
}

// ---------------- CSR build (r4-verified): cells + direct self-loop insertion ----
// binA block k writes bucket-b records to cell (b,k), CELL=64 capacity. Only the
// 800K REAL edges stream through binA (Poisson(21)/cell -> P(>64)~1e-14); the
// 50K self-loops are inserted by binB at slot 0 of each node's range.
// cnts[b][k] fully overwritten each run -> NO pre-zeroing, NO detect dispatch:
// each binA block does its own 64-sample dtype detect; block 0 publishes flags.
// wt (weight split/frag-reorder) fused as tail: NBA*256 = 50176 >= 49152.

__global__ __launch_bounds__(256) void binA_kernel(
    const void* __restrict__ ei, unsigned* __restrict__ pairs,
    int* __restrict__ cnts, int* __restrict__ flags,
    const void* __restrict__ x,
    const void* __restrict__ W1, const void* __restrict__ W2,
    ushort* __restrict__ wt1, ushort* __restrict__ wt2) {
    __shared__ int cnt[256], lofs[256], pcur[256];
    __shared__ unsigned stage[EPB];
    __shared__ int s_i64, s_f32;
    int t = threadIdx.x;

    // ---- inline dtype detect: wave0 -> i64 flag, wave1 -> f32 flag ----
    if (t < 64) {
        const unsigned* wu = (const unsigned*)ei;
        long j = 1 + (long)t * 24986;           // odd dwords, < 1.6M (int32-safe)
        unsigned long long bal = __ballot(wu[j] != 0u);
        if (t == 0) s_i64 = (__popcll(bal) < 16) ? 1 : 0;   // i64: high words all 0
    } else if (t < 128) {
        const unsigned* xu = (const unsigned*)x;
        unsigned u = xu[(long)(t - 64) * 100000];           // < 6.4M dwords (bf16-safe)
        unsigned e = (u >> 23) & 0xFF;
        unsigned long long bal = __ballot(u == 0u || (e >= 100 && e <= 140));
        if (t == 64) s_f32 = (__popcll(bal) >= 32) ? 1 : 0;
    }
    cnt[t] = 0;
    __syncthreads();
    int i64 = s_i64, f32 = s_f32;
    if (blockIdx.x == 0 && t == 0) { flags[0] = f32; flags[1] = i64; }

    int e0 = blockIdx.x * EPB;
    int nE = min(EPB, N_EDGES - e0);
    int sj[EPB / 256], dj[EPB / 256];
#pragma unroll
    for (int j = 0; j < EPB / 256; j++) {
        int idx = j * 256 + t;
        if (idx < nE) {
            edge_sd(ei, e0 + idx, i64, sj[j], dj[j]);
            atomicAdd(&cnt[dj[j] >> 8], 1);
        } else dj[j] = -1;
    }
    __syncthreads();
    lofs[t] = cnt[t];
    for (int off = 1; off < 256; off <<= 1) {
        __syncthreads();
        int v = (t >= off) ? lofs[t - off] : 0;
        __syncthreads();
        lofs[t] += v;
    }
    __syncthreads();
    int excl = lofs[t] - cnt[t];
    __syncthreads();
    lofs[t] = excl;
    pcur[t] = excl;
    __syncthreads();
#pragma unroll
    for (int j = 0; j < EPB / 256; j++) {
        if (dj[j] >= 0) {
            int b = dj[j] >> 8;
            int lp = atomicAdd(&pcur[b], 1);
            stage[lp] = (unsigned)sj[j] | ((unsigned)(dj[j] & 255) << 16) |
                        ((unsigned)b << 24);
        }
    }
    __syncthreads();
    for (int i = t; i < nE; i += 256) {      // per-bucket contiguous cell writes
        unsigned p = stage[i];
        int b = p >> 24;
        int off2 = i - lofs[b];
        if (off2 < CELL)
            pairs[((size_t)b * NBA + blockIdx.x) * CELL + off2] = p;
    }
    if (t < NBUCK) cnts[(size_t)t * NBA + blockIdx.x] = min(cnt[t], CELL);

    // ---- fused wt tail: split-bf16 (hi+lo) frag-reorder of W1,W2 ----
    int wi = blockIdx.x * 256 + t;
    if (wi < IN_F * G + G * G) {
        const void* W; ushort* wtp; int idx;
        if (wi < IN_F * G) { W = W1; wtp = wt1; idx = wi; }
        else { W = W2; wtp = wt2; idx = wi - IN_F * G; }
        int k = idx >> 7, n = idx & (G - 1);
        float wv = ldf(W, idx, f32);
        ushort h = f2bf(wv);
        ushort lo = f2bf(wv - bf2f(h));
        int c = k >> 5, q = (k >> 3) & 3, j = k & 7;
        int nt = n >> 4, n16 = n & 15;
        int lane = q * 16 + n16;
        size_t base = ((size_t)c * 16 + nt * 2) * 512 + lane * 8 + j;
        wtp[base] = h;           // hilo = 0
        wtp[base + 512] = lo;    // hilo = 1
    }
}

// binB (r4-verified): per-bucket node counts+scan -> rowse, self-loop at slot 0,
// scatter srcs (ushort) from cells.
__device__ __forceinline__ void binB_body(
    const unsigned* __restrict__ pairs, const int* __restrict__ cnts,
    int2* __restrict__ rowse, ushort* __restrict__ srcs,
    int b, int t, int* cnt, int* cur, int* ccnt) {
    if (t < NBA) ccnt[t] = cnts[(size_t)b * NBA + t];
    int node = b * 256 + t;
    int valid = (node < N_NODES) ? 1 : 0;
    cnt[t] = valid;                        // reserve the self-loop slot
    __syncthreads();
    if (t < NBA) {                         // thread t streams cell (b,t), 4-batched
        const unsigned* cp = pairs + ((size_t)b * NBA + t) * CELL;
        int n = ccnt[t], i = 0;
        for (; i + 4 <= n; i += 4) {
            unsigned r0 = cp[i], r1 = cp[i + 1], r2 = cp[i + 2], r3 = cp[i + 3];
            atomicAdd(&cnt[(r0 >> 16) & 255], 1);
            atomicAdd(&cnt[(r1 >> 16) & 255], 1);
            atomicAdd(&cnt[(r2 >> 16) & 255], 1);
            atomicAdd(&cnt[(r3 >> 16) & 255], 1);
        }
        for (; i < n; i++) atomicAdd(&cnt[(cp[i] >> 16) & 255], 1);
    }
    __syncthreads();
    cur[t] = cnt[t];
    for (int off = 1; off < 256; off <<= 1) {
        __syncthreads();
        int v = (t >= off) ? cur[t - off] : 0;
        __syncthreads();
        cur[t] += v;
    }
    int excl = cur[t] - cnt[t];
    int base = b * CAPB;
    int myCnt = cnt[t];
    __syncthreads();
    if (valid) {
        srcs[base + excl] = (ushort)node;  // self-loop at slot 0
        rowse[node] = make_int2(base + excl, base + excl + myCnt);
    }
    cur[t] = base + excl + valid;
    __syncthreads();
    if (t < NBA) {
        const unsigned* cp = pairs + ((size_t)b * NBA + t) * CELL;
        int n = ccnt[t], i = 0;
        for (; i + 4 <= n; i += 4) {
            unsigned r0 = cp[i], r1 = cp[i + 1], r2 = cp[i + 2], r3 = cp[i + 3];
            int p0 = atomicAdd(&cur[(r0 >> 16) & 255], 1);
            int p1 = atomicAdd(&cur[(r1 >> 16) & 255], 1);
            int p2 = atomicAdd(&cur[(r2 >> 16) & 255], 1);
            int p3 = atomicAdd(&cur[(r3 >> 16) & 255], 1);
            srcs[p0] = (ushort)(r0 & 0xFFFFu);
            srcs[p1] = (ushort)(r1 & 0xFFFFu);
            srcs[p2] = (ushort)(r2 & 0xFFFFu);
            srcs[p3] = (ushort)(r3 & 0xFFFFu);
        }
        for (; i < n; i++) {
            unsigned r = cp[i];
            int p = atomicAdd(&cur[(r >> 16) & 255], 1);
            srcs[p] = (ushort)(r & 0xFFFFu);
        }
    }
}

// ---------------- GEMM: MFMA split-bf16 (hi+lo) with frag-ordered W ----------------
// Block 256 thr = 4 waves; wave = 16 rows x 128 cols.
// H2: packed bf16x2, word l = {f_l, f_{l+64}}; es2[n] = {es, ed} (float2).
template <int K, bool AF32>
__device__ __forceinline__ void gemm_body(
    int bid, const void* __restrict__ A, const ushort* __restrict__ wt,
    unsigned* __restrict__ H2, const int* __restrict__ flags,
    const void* __restrict__ aS, const void* __restrict__ aD,
    float2* __restrict__ es2, short8* sB8) {
    constexpr int NC = K / 32;
    int wave = threadIdx.x >> 6, lane = threadIdx.x & 63;
    int quad = lane >> 4, n16 = lane & 15;
    int rb = bid * 64 + wave * 16;
    int rowa = min(rb + n16, N_NODES - 1);
    f32x4 acc[8];
#pragma unroll
    for (int t = 0; t < 8; t++) acc[t] = (f32x4){0.f, 0.f, 0.f, 0.f};

    for (int c = 0; c < NC; c++) {
#pragma unroll
        for (int i = 0; i < 4; i++) {
            int fw = wave * 4 + i;
            stage16(wt + ((size_t)c * 16 + fw) * 512 + lane * 8, &sB8[fw * 64]);
        }
        float av[8];
        if (AF32) {
            const float* ap = (const float*)A + (size_t)rowa * K + c * 32 + quad * 8;
            f32x4 a0 = *(const f32x4*)ap;
            f32x4 a1 = *(const f32x4*)(ap + 4);
#pragma unroll
            for (int j = 0; j < 4; j++) { av[j] = a0[j]; av[j + 4] = a1[j]; }
        } else {
            const ushort* ap = (const ushort*)A + (size_t)rowa * K + c * 32 + quad * 8;
#pragma unroll
            for (int j = 0; j < 8; j++) av[j] = bf2f(ap[j]);
        }
        short8 ahi, alo;
#pragma unroll
        for (int j = 0; j < 8; j++) {
            ushort h = f2bf(av[j]);
            ahi[j] = (short)h;
            alo[j] = (short)f2bf(av[j] - bf2f(h));
        }
        __syncthreads();   // staging complete
#pragma unroll
        for (int nt = 0; nt < 8; nt++) {
            short8 bh = sB8[(nt * 2 + 0) * 64 + lane];
            short8 bl = sB8[(nt * 2 + 1) * 64 + lane];
            acc[nt] = __builtin_amdgcn_mfma_f32_16x16x32_bf16(ahi, bh, acc[nt], 0, 0, 0);
            acc[nt] = __builtin_amdgcn_mfma_f32_16x16x32_bf16(ahi, bl, acc[nt], 0, 0, 0);
            acc[nt] = __builtin_amdgcn_mfma_f32_16x16x32_bf16(alo, bh, acc[nt], 0, 0, 0);
        }
        __syncthreads();
    }

    // epilogue: packed-bf16 H2 store + fused ead (es2 = {h.as, h.ad})
    int f32 = flags[0];
    float asv[8], adv[8];
#pragma unroll
    for (int nt = 0; nt < 8; nt++) {
        asv[nt] = ldf(aS, nt * 16 + n16, f32);
        adv[nt] = ldf(aD, nt * 16 + n16, f32);
    }
#pragma unroll
    for (int r = 0; r < 4; r++) {
        int ro = rb + quad * 4 + r;
        float s = 0.f, dv = 0.f;
#pragma unroll
        for (int nt = 0; nt < 8; nt++) {
            s += acc[nt][r] * asv[nt];
            dv += acc[nt][r] * adv[nt];
        }
        if (ro < N_NODES) {
#pragma unroll
            for (int nt = 0; nt < 4; nt++) {   // word c = {f_c, f_{c+64}}
                unsigned pack = (unsigned)f2bf(acc[nt][r]) |
                                ((unsigned)f2bf(acc[nt + 4][r]) << 16);
                H2[(size_t)ro * 64 + nt * 16 + n16] = pack;
            }
        }
#pragma unroll
        for (int off = 8; off; off >>= 1) {
            s += __shfl_xor(s, off);
            dv += __shfl_xor(dv, off);
        }
        if (n16 == 0 && ro < N_NODES) es2[ro] = make_float2(s, dv);
    }
}

// hybrid dispatch: blocks [0,NBUCK) run binB; blocks [NBUCK, NBUCK+gemm_grid)
// run layer-1 GEMM (independent work; binB hides under gemm1).
template <int K>
__global__ __launch_bounds__(256, 3) void binB_gemm_kernel(
    const unsigned* __restrict__ pairs, const int* __restrict__ cnts,
    int2* __restrict__ rowse, ushort* __restrict__ srcs,
    const void* __restrict__ A, const ushort* __restrict__ wt,
    unsigned* __restrict__ H2, const int* __restrict__ flags,
    const void* __restrict__ aS, const void* __restrict__ aD,
    float2* __restrict__ es2) {
    __shared__ short8 sB8[16 * 64];   // 16 KB (gemm blocks)
    __shared__ int s_cnt[256], s_cur[256], s_ccnt[NBA];
    if (blockIdx.x < NBUCK) {
        binB_body(pairs, cnts, rowse, srcs, blockIdx.x, threadIdx.x,
                  s_cnt, s_cur, s_ccnt);
        return;
    }
    int bid = blockIdx.x - NBUCK;
    if (flags[0]) gemm_body<K, true>(bid, A, wt, H2, flags, aS, aD, es2, sB8);
    else          gemm_body<K, false>(bid, A, wt, H2, flags, aS, aD, es2, sB8);
}

// layer-2 GEMM; block 0 also zeroes gsum/gcnt/done for the fused pool+head
// dispatch two slots later (r3-proven pattern; stream-ordered).
template <int K>
__global__ __launch_bounds__(256, 3) void gemm_mfma_kernel(
    const void* __restrict__ A, const ushort* __restrict__ wt,
    unsigned* __restrict__ H2, int a_mode, const int* __restrict__ flags,
    const void* __restrict__ aS, const void* __restrict__ aD,
    float2* __restrict__ es2, float* __restrict__ gsum, float* __restrict__ gcnt,
    int* __restrict__ done) {
    __shared__ short8 sB8[16 * 64];   // 16 frags x 1 KB = 16 KB
    if (blockIdx.x == 0) {
        for (int i = threadIdx.x; i < NGRAPH * G; i += 256) gsum[i] = 0.f;
        if (threadIdx.x < NGRAPH) gcnt[threadIdx.x] = 0.f;
        if (threadIdx.x == 0) done[0] = 0;
    }
    int af32 = (a_mode == 2) ? 0 : flags[0];   // block-uniform
    if (af32) gemm_body<K, true>(blockIdx.x, A, wt, H2, flags, aS, aD, es2, sB8);
    else      gemm_body<K, false>(blockIdx.x, A, wt, H2, flags, aS, aD, es2, sB8);
}

// Fused GAT aggregate v4: 4 waves/block, no LDS/barriers,
// 8-deep explicit gather batching, bf16 output. (v5: ushort srcs, int2 rowse)
// NOTE (r9 lesson): keep this a single plain kernel — adding POOL variants
// (runtime or co-compiled template) regressed its codegen ~4x (r3-r9).
// BYTE-IDENTICAL to the r10/r11/r12 anchor.
__global__ __launch_bounds__(256) void gat_agg_kernel(
    const unsigned* __restrict__ h2, const int2* __restrict__ rowse,
    const ushort* __restrict__ srcs, const float2* __restrict__ es2,
    const void* __restrict__ bias, ushort* __restrict__ outb,
    const int* __restrict__ flags) {
    int node = blockIdx.x * 4 + (threadIdx.x >> 6);
    if (node >= N_NODES) return;            // wave-uniform: all 64 lanes stay active
    int l = threadIdx.x & 63;
    int2 se = rowse[node];
    int start = se.x, end = se.y;
    float edd = es2[node].y;
    float m = -INFINITY, den = 0.f;
    float acc0 = 0.f, acc1 = 0.f;
    for (int c0 = start; c0 < end; c0 += 64) {
        int cn = min(end - c0, 64);
        int s = 0; float v = -INFINITY;
        if (l < cn) {
            s = (int)srcs[c0 + l];
            v = es2[s].x + edd;
            v = v >= 0.f ? v : 0.2f * v;    // LeakyReLU(0.2)
        }
        float mc = v;
#pragma unroll
        for (int off = 32; off; off >>= 1) mc = fmaxf(mc, __shfl_xor(mc, off));
        float mnew = fmaxf(m, mc);
        float scale = expf(m - mnew);        // m=-INF first chunk -> 0
        float p = (l < cn) ? expf(v - mnew) : 0.f;
        float lsum = p;
#pragma unroll
        for (int off = 32; off; off >>= 1) lsum += __shfl_xor(lsum, off);
        den = den * scale + lsum;
        acc0 *= scale; acc1 *= scale;
        int cnr = (cn + 7) & ~7;             // round up: tail lanes have p=0
        for (int i = 0; i < cnr; i += 8) {
            int sis[8]; float pis[8]; unsigned hv[8];
#pragma unroll
            for (int j = 0; j < 8; j++) {
                sis[j] = __builtin_amdgcn_readlane(s, i + j);
                pis[j] = __uint_as_float(
                    __builtin_amdgcn_readlane(__float_as_uint(p), i + j));
            }
#pragma unroll
            for (int j = 0; j < 8; j++)      // 8 outstanding 256B wave-loads
                hv[j] = h2[(size_t)sis[j] * 64 + l];
#pragma unroll
            for (int j = 0; j < 8; j++) {
                acc0 += pis[j] * bf2f((ushort)(hv[j] & 0xFFFFu));
                acc1 += pis[j] * bf2f((ushort)(hv[j] >> 16));
            }
        }
        m = mnew;
    }
    float inv = 1.f / (den + 1e-16f);
    int f32 = flags[0];
    float o0 = acc0 * inv + ldf(bias, l, f32);
    float o1 = acc1 * inv + ldf(bias, l + 64, f32);
    outb[(size_t)node * G + l]      = f2bf(selu_f(o0));
    outb[(size_t)node * G + l + 64] = f2bf(selu_f(o1));
}

// ---------------- fused pool + head (last-block pattern) ----------------
// Pool phase: r12 pool_kernel arithmetic verbatim (atomic gsum/gcnt).
// Then each block bumps `done`; the LAST block runs the head inline, reading
// gsum/gcnt via atomicAdd(p, 0.f) (device-scope coherent across XCD L2s).
__global__ void pool_head_kernel(const ushort* __restrict__ h, const void* __restrict__ batch,
                                 float* __restrict__ gsum, float* __restrict__ gcnt,
                                 int* __restrict__ done,
                                 const void* __restrict__ lw1, const void* __restrict__ lb1,
                                 const void* __restrict__ lw2, const void* __restrict__ lb2,
                                 float* __restrict__ out, const int* __restrict__ flags) {
    int t = threadIdx.x;  // 128
    int f32 = flags[0], i64 = flags[1];
    int i0 = blockIdx.x * POOL_NODES;
    int i1 = min(N_NODES, i0 + POOL_NODES);
    int cur = -1, runLen = 0;
    float acc = 0.f;
    for (int i = i0; i < i1; i++) {
        int g = min(max(ldi(batch, i, i64), 0), NGRAPH - 1);
        if (g != cur) {
            if (cur >= 0) {
                atomicAdd(&gsum[cur * G + t], acc);
                if (t == 0) atomicAdd(&gcnt[cur], (float)runLen);
            }
            cur = g; acc = 0.f; runLen = 0;
        }
        acc += bf2f(h[(size_t)i * G + t]);
        runLen++;
    }
    if (cur >= 0) {
        atomicAdd(&gsum[cur * G + t], acc);
        if (t == 0) atomicAdd(&gcnt[cur], (float)runLen);
    }

    // ---- last-block head ----
    __shared__ int isLast;
    __threadfence();                      // publish this block's atomics
    if (t == 0) isLast = (atomicAdd(done, 1) == (int)gridDim.x - 1) ? 1 : 0;
    __syncthreads();
    if (!isLast) return;

    __shared__ float z[G];
    __shared__ float z1[NHID];
    __shared__ float z2[2];
    for (int g = 0; g < NGRAPH; g++) {
        float cnt = fmaxf(atomicAdd(&gcnt[g], 0.f), 1.0f);
        z[t] = selu_f(atomicAdd(&gsum[g * G + t], 0.f) / cnt);   // t covers all G=128
        __syncthreads();
        if (t < NHID) {
            float a = ldf(lb1, t, f32);
            for (int k = 0; k < G; k++) a += z[k] * ldf(lw1, k * NHID + t, f32);
            z1[t] = selu_f(a);
        }
        __syncthreads();
        if (t < 2) {
            float s = ldf(lb2, t, f32);
            for (int j = 0; j < NHID; j++) s += z1[j] * ldf(lw2, j * 2 + t, f32);
            z2[t] = s;
        }
        __syncthreads();
        if (t == 0) {
            float mx = fmaxf(z2[0], z2[1]);
            float l = mx + logf(expf(z2[0] - mx) + expf(z2[1] - mx));
            out[g * 2 + 0] = z2[0] - l;
            out[g * 2 + 1] = z2[1] - l;
        }
        __syncthreads();
    }
}

extern "C" void kernel_launch(void* const* d_in, const int* in_sizes, int n_in,
                              void* d_out, int out_size, void* d_ws, size_t ws_size,
                              hipStream_t stream) {
    const void* x    = d_in[0];
    const void* ei   = d_in[1];
    const void* batch= d_in[2];
    const void* W1   = d_in[3];
    const void* as1  = d_in[4];
    const void* ad1  = d_in[5];
    const void* b1   = d_in[6];
    const void* W2   = d_in[7];
    const void* as2  = d_in[8];
    const void* ad2  = d_in[9];
    const void* b2   = d_in[10];
    const void* lw1  = d_in[11];
    const void* lb1  = d_in[12];
    const void* lw2  = d_in[13];
    const void* lb2  = d_in[14];
    float* out = (float*)d_out;

    char* w = (char*)d_ws;
    size_t off = 0;
    auto alloc = [&](size_t bytes) -> char* {
        char* p = w + off;
        off = (off + bytes + 255) & ~(size_t)255;
        return p;
    };
    int*      flags  = (int*)alloc(256);
    int*      done   = (int*)alloc(256);
    unsigned* h2     = (unsigned*)alloc((size_t)N_NODES * 64 * 4);  // packed bf16x2
    ushort*   abuf   = (ushort*)alloc((size_t)N_NODES * G * 2);     // bf16 activations
    float2*   es2    = (float2*)alloc((size_t)N_NODES * 8);
    int2*     rowse  = (int2*)alloc((size_t)N_NODES * 8);
    unsigned* pairs  = (unsigned*)alloc((size_t)NBUCK * NBA * CELL * 4);  // 9.8 MB
    int*      cnts   = (int*)alloc((size_t)NBUCK * NBA * 4);
    ushort*   srcs   = (ushort*)alloc((size_t)NBUCK * CAPB * 2);
    float*    gsum   = (float*)alloc((size_t)NGRAPH * G * 4);
    float*    gcnt   = (float*)alloc((size_t)NGRAPH * 4);
    ushort*   wt1    = (ushort*)alloc((size_t)IN_F * G * 2 * 2);   // hi+lo frag-ordered
    ushort*   wt2    = (ushort*)alloc((size_t)G * G * 2 * 2);

    unsigned gemm_grid = (N_NODES + 63) / 64;   // 782
    unsigned agg_grid = (N_NODES + 3) / 4;      // 12500
    unsigned pool_grid = (N_NODES + POOL_NODES - 1) / POOL_NODES;  // 782

    // 1. edge bucketing (+ inline dtype detect, flags publish, fused wt tail)
    binA_kernel<<<NBA, 256, 0, stream>>>(ei, pairs, cnts, flags, x, W1, W2, wt1, wt2);
    // 2. hybrid: binB (CSR finalize + self-loops) + layer-1 GEMM
    binB_gemm_kernel<IN_F><<<NBUCK + gemm_grid, 256, 0, stream>>>(
        pairs, cnts, rowse, srcs, x, wt1, h2, flags, as1, ad1, es2);
    // 3. layer-1 aggregate -> abuf
    gat_agg_kernel<<<agg_grid, 256, 0, stream>>>(h2, rowse, srcs, es2, b1, abuf, flags);
    // 4. layer-2 GEMM (+ gsum/gcnt/done zero by block 0)
    gemm_mfma_kernel<G><<<gemm_grid, 256, 0, stream>>>(abuf, wt2, h2, 2, flags,
                                                       as2, ad2, es2, gsum, gcnt, done);
    // 5. layer-2 aggregate
    gat_agg_kernel<<<agg_grid, 256, 0, stream>>>(h2, rowse, srcs, es2, b2, abuf, flags);
    // 6. fused pool + head (last block runs the head)
    pool_head_kernel<<<pool_grid, 128, 0, stream>>>(abuf, batch, gsum, gcnt, done,
                                                    lw1, lb1, lw2, lb2, out, flags);
}

// Round 15
// 355.404 us; speedup vs baseline: 1.6710x; 1.6710x over previous
//
#include <hip/hip_runtime.h>
#include <hip/hip_bf16.h>
#include <math.h>

#define N_NODES 50000
#define N_EDGES 800000
#define IN_F 256
#define G 128                    // 2*HID
#define NHID 64
#define NGRAPH 32
#define NBUCK ((N_NODES + 255) / 256)    // 196 buckets (dst>>8)
#define CAPB 8192                         // srcs capacity per bucket (mean 4352+256)
#define CELL 64                           // pairs capacity per (bucket, binA-block)
#define POOL_NODES 64
#define EPB 4096                          // edges per binA block
#define NBA ((N_EDGES + EPB - 1) / EPB)   // 196 (real edges only; self-loops direct)

typedef __hip_bfloat16 bf16;
typedef unsigned short ushort;
typedef __attribute__((ext_vector_type(8))) short short8;
typedef __attribute__((ext_vector_type(4))) float f32x4;

// ---------- dtype-agnostic loads ----------
__device__ __forceinline__ float bf2f(ushort u) {
    union { unsigned u; float f; } c; c.u = ((unsigned)u) << 16; return c.f;
}
// round-to-nearest-even f32 -> bf16 (finite inputs)
__device__ __forceinline__ ushort f2bf(float f) {
    unsigned u = __float_as_uint(f);
    u += 0x7FFFu + ((u >> 16) & 1u);
    return (ushort)(u >> 16);
}
__device__ __forceinline__ float ldf(const void* p, long i, int f32) {
    return f32 ? ((const float*)p)[i] : bf2f(((const ushort*)p)[i]);
}
__device__ __forceinline__ int ldi(const void* p, long i, int i64) {
    return i64 ? (int)((const long long*)p)[i] : ((const int*)p)[i];
}

__device__ __forceinline__ float selu_f(float x) {
    const float sc = 1.0507009873554805f, al = 1.6732632423543772f;
    return x > 0.f ? sc * x : sc * al * expm1f(x);
}

// async global->LDS, 16 B/lane; lds base must be wave-uniform.
typedef const __attribute__((address_space(1))) void gas_void;
typedef __attribute__((address_space(3))) void las_void;
__device__ __forceinline__ void stage16(const void* g, void* l) {
    __builtin_amdgcn_global_load_lds((gas_void*)g, (las_void*)l, 16, 0, 0);
}

__device__ __forceinline__ void edge_sd(const void* __restrict__ ei, int e, int i64,
                                        int& s, int& d) {
    s = ldi(ei, e, i64);
    d = ldi(ei, (long)N_EDGES + e, i64);
    s = min(max(s, 0), N_NODES - 1);
    d = min(max(d, 0), N_NODES - 1);
}

// ---------------- CSR build (r4-verified): cells + direct self-loop insertion ----
// binA block k writes bucket-b records to cell (b,k), CELL=64 capacity. Only the
// 800K REAL edges stream through binA (Poisson(21)/cell -> P(>64)~1e-14); the
// 50K self-loops are inserted by binB at slot 0 of each node's range.
// cnts[b][k] fully overwritten each run -> NO pre-zeroing, NO detect dispatch:
// each binA block does its own 64-sample dtype detect; block 0 publishes flags.
// wt (weight split/frag-reorder) fused as tail: NBA*256 = 50176 >= 49152.

__global__ __launch_bounds__(256) void binA_kernel(
    const void* __restrict__ ei, unsigned* __restrict__ pairs,
    int* __restrict__ cnts, int* __restrict__ flags,
    const void* __restrict__ x,
    const void* __restrict__ W1, const void* __restrict__ W2,
    ushort* __restrict__ wt1, ushort* __restrict__ wt2) {
    __shared__ int cnt[256], lofs[256], pcur[256];
    __shared__ unsigned stage[EPB];
    __shared__ int s_i64, s_f32;
    int t = threadIdx.x;

    // ---- inline dtype detect: wave0 -> i64 flag, wave1 -> f32 flag ----
    if (t < 64) {
        const unsigned* wu = (const unsigned*)ei;
        long j = 1 + (long)t * 24986;           // odd dwords, < 1.6M (int32-safe)
        unsigned long long bal = __ballot(wu[j] != 0u);
        if (t == 0) s_i64 = (__popcll(bal) < 16) ? 1 : 0;   // i64: high words all 0
    } else if (t < 128) {
        const unsigned* xu = (const unsigned*)x;
        unsigned u = xu[(long)(t - 64) * 100000];           // < 6.4M dwords (bf16-safe)
        unsigned e = (u >> 23) & 0xFF;
        unsigned long long bal = __ballot(u == 0u || (e >= 100 && e <= 140));
        if (t == 64) s_f32 = (__popcll(bal) >= 32) ? 1 : 0;
    }
    cnt[t] = 0;
    __syncthreads();
    int i64 = s_i64, f32 = s_f32;
    if (blockIdx.x == 0 && t == 0) { flags[0] = f32; flags[1] = i64; }

    int e0 = blockIdx.x * EPB;
    int nE = min(EPB, N_EDGES - e0);
    int sj[EPB / 256], dj[EPB / 256];
#pragma unroll
    for (int j = 0; j < EPB / 256; j++) {
        int idx = j * 256 + t;
        if (idx < nE) {
            edge_sd(ei, e0 + idx, i64, sj[j], dj[j]);
            atomicAdd(&cnt[dj[j] >> 8], 1);
        } else dj[j] = -1;
    }
    __syncthreads();
    lofs[t] = cnt[t];
    for (int off = 1; off < 256; off <<= 1) {
        __syncthreads();
        int v = (t >= off) ? lofs[t - off] : 0;
        __syncthreads();
        lofs[t] += v;
    }
    __syncthreads();
    int excl = lofs[t] - cnt[t];
    __syncthreads();
    lofs[t] = excl;
    pcur[t] = excl;
    __syncthreads();
#pragma unroll
    for (int j = 0; j < EPB / 256; j++) {
        if (dj[j] >= 0) {
            int b = dj[j] >> 8;
            int lp = atomicAdd(&pcur[b], 1);
            stage[lp] = (unsigned)sj[j] | ((unsigned)(dj[j] & 255) << 16) |
                        ((unsigned)b << 24);
        }
    }
    __syncthreads();
    for (int i = t; i < nE; i += 256) {      // per-bucket contiguous cell writes
        unsigned p = stage[i];
        int b = p >> 24;
        int off2 = i - lofs[b];
        if (off2 < CELL)
            pairs[((size_t)b * NBA + blockIdx.x) * CELL + off2] = p;
    }
    if (t < NBUCK) cnts[(size_t)t * NBA + blockIdx.x] = min(cnt[t], CELL);

    // ---- fused wt tail: split-bf16 (hi+lo) frag-reorder of W1,W2 ----
    int wi = blockIdx.x * 256 + t;
    if (wi < IN_F * G + G * G) {
        const void* W; ushort* wtp; int idx;
        if (wi < IN_F * G) { W = W1; wtp = wt1; idx = wi; }
        else { W = W2; wtp = wt2; idx = wi - IN_F * G; }
        int k = idx >> 7, n = idx & (G - 1);
        float wv = ldf(W, idx, f32);
        ushort h = f2bf(wv);
        ushort lo = f2bf(wv - bf2f(h));
        int c = k >> 5, q = (k >> 3) & 3, j = k & 7;
        int nt = n >> 4, n16 = n & 15;
        int lane = q * 16 + n16;
        size_t base = ((size_t)c * 16 + nt * 2) * 512 + lane * 8 + j;
        wtp[base] = h;           // hilo = 0
        wtp[base + 512] = lo;    // hilo = 1
    }
}

// binB (r4-verified): per-bucket node counts+scan -> rowse, self-loop at slot 0,
// scatter srcs (ushort) from cells.
__device__ __forceinline__ void binB_body(
    const unsigned* __restrict__ pairs, const int* __restrict__ cnts,
    int2* __restrict__ rowse, ushort* __restrict__ srcs,
    int b, int t, int* cnt, int* cur, int* ccnt) {
    if (t < NBA) ccnt[t] = cnts[(size_t)b * NBA + t];
    int node = b * 256 + t;
    int valid = (node < N_NODES) ? 1 : 0;
    cnt[t] = valid;                        // reserve the self-loop slot
    __syncthreads();
    if (t < NBA) {                         // thread t streams cell (b,t), 4-batched
        const unsigned* cp = pairs + ((size_t)b * NBA + t) * CELL;
        int n = ccnt[t], i = 0;
        for (; i + 4 <= n; i += 4) {
            unsigned r0 = cp[i], r1 = cp[i + 1], r2 = cp[i + 2], r3 = cp[i + 3];
            atomicAdd(&cnt[(r0 >> 16) & 255], 1);
            atomicAdd(&cnt[(r1 >> 16) & 255], 1);
            atomicAdd(&cnt[(r2 >> 16) & 255], 1);
            atomicAdd(&cnt[(r3 >> 16) & 255], 1);
        }
        for (; i < n; i++) atomicAdd(&cnt[(cp[i] >> 16) & 255], 1);
    }
    __syncthreads();
    cur[t] = cnt[t];
    for (int off = 1; off < 256; off <<= 1) {
        __syncthreads();
        int v = (t >= off) ? cur[t - off] : 0;
        __syncthreads();
        cur[t] += v;
    }
    int excl = cur[t] - cnt[t];
    int base = b * CAPB;
    int myCnt = cnt[t];
    __syncthreads();
    if (valid) {
        srcs[base + excl] = (ushort)node;  // self-loop at slot 0
        rowse[node] = make_int2(base + excl, base + excl + myCnt);
    }
    cur[t] = base + excl + valid;
    __syncthreads();
    if (t < NBA) {
        const unsigned* cp = pairs + ((size_t)b * NBA + t) * CELL;
        int n = ccnt[t], i = 0;
        for (; i + 4 <= n; i += 4) {
            unsigned r0 = cp[i], r1 = cp[i + 1], r2 = cp[i + 2], r3 = cp[i + 3];
            int p0 = atomicAdd(&cur[(r0 >> 16) & 255], 1);
            int p1 = atomicAdd(&cur[(r1 >> 16) & 255], 1);
            int p2 = atomicAdd(&cur[(r2 >> 16) & 255], 1);
            int p3 = atomicAdd(&cur[(r3 >> 16) & 255], 1);
            srcs[p0] = (ushort)(r0 & 0xFFFFu);
            srcs[p1] = (ushort)(r1 & 0xFFFFu);
            srcs[p2] = (ushort)(r2 & 0xFFFFu);
            srcs[p3] = (ushort)(r3 & 0xFFFFu);
        }
        for (; i < n; i++) {
            unsigned r = cp[i];
            int p = atomicAdd(&cur[(r >> 16) & 255], 1);
            srcs[p] = (ushort)(r & 0xFFFFu);
        }
    }
}

// ---------------- GEMM: MFMA split-bf16 (hi+lo) with frag-ordered W ----------------
// Block 256 thr = 4 waves; wave = 16 rows x 128 cols.
// H2: packed bf16x2, word l = {f_l, f_{l+64}}; es2[n] = {es, ed} (float2).
template <int K, bool AF32>
__device__ __forceinline__ void gemm_body(
    int bid, const void* __restrict__ A, const ushort* __restrict__ wt,
    unsigned* __restrict__ H2, const int* __restrict__ flags,
    const void* __restrict__ aS, const void* __restrict__ aD,
    float2* __restrict__ es2, short8* sB8) {
    constexpr int NC = K / 32;
    int wave = threadIdx.x >> 6, lane = threadIdx.x & 63;
    int quad = lane >> 4, n16 = lane & 15;
    int rb = bid * 64 + wave * 16;
    int rowa = min(rb + n16, N_NODES - 1);
    f32x4 acc[8];
#pragma unroll
    for (int t = 0; t < 8; t++) acc[t] = (f32x4){0.f, 0.f, 0.f, 0.f};

    for (int c = 0; c < NC; c++) {
#pragma unroll
        for (int i = 0; i < 4; i++) {
            int fw = wave * 4 + i;
            stage16(wt + ((size_t)c * 16 + fw) * 512 + lane * 8, &sB8[fw * 64]);
        }
        float av[8];
        if (AF32) {
            const float* ap = (const float*)A + (size_t)rowa * K + c * 32 + quad * 8;
            f32x4 a0 = *(const f32x4*)ap;
            f32x4 a1 = *(const f32x4*)(ap + 4);
#pragma unroll
            for (int j = 0; j < 4; j++) { av[j] = a0[j]; av[j + 4] = a1[j]; }
        } else {
            const ushort* ap = (const ushort*)A + (size_t)rowa * K + c * 32 + quad * 8;
#pragma unroll
            for (int j = 0; j < 8; j++) av[j] = bf2f(ap[j]);
        }
        short8 ahi, alo;
#pragma unroll
        for (int j = 0; j < 8; j++) {
            ushort h = f2bf(av[j]);
            ahi[j] = (short)h;
            alo[j] = (short)f2bf(av[j] - bf2f(h));
        }
        __syncthreads();   // staging complete
#pragma unroll
        for (int nt = 0; nt < 8; nt++) {
            short8 bh = sB8[(nt * 2 + 0) * 64 + lane];
            short8 bl = sB8[(nt * 2 + 1) * 64 + lane];
            acc[nt] = __builtin_amdgcn_mfma_f32_16x16x32_bf16(ahi, bh, acc[nt], 0, 0, 0);
            acc[nt] = __builtin_amdgcn_mfma_f32_16x16x32_bf16(ahi, bl, acc[nt], 0, 0, 0);
            acc[nt] = __builtin_amdgcn_mfma_f32_16x16x32_bf16(alo, bh, acc[nt], 0, 0, 0);
        }
        __syncthreads();
    }

    // epilogue: packed-bf16 H2 store + fused ead (es2 = {h.as, h.ad})
    int f32 = flags[0];
    float asv[8], adv[8];
#pragma unroll
    for (int nt = 0; nt < 8; nt++) {
        asv[nt] = ldf(aS, nt * 16 + n16, f32);
        adv[nt] = ldf(aD, nt * 16 + n16, f32);
    }
#pragma unroll
    for (int r = 0; r < 4; r++) {
        int ro = rb + quad * 4 + r;
        float s = 0.f, dv = 0.f;
#pragma unroll
        for (int nt = 0; nt < 8; nt++) {
            s += acc[nt][r] * asv[nt];
            dv += acc[nt][r] * adv[nt];
        }
        if (ro < N_NODES) {
#pragma unroll
            for (int nt = 0; nt < 4; nt++) {   // word c = {f_c, f_{c+64}}
                unsigned pack = (unsigned)f2bf(acc[nt][r]) |
                                ((unsigned)f2bf(acc[nt + 4][r]) << 16);
                H2[(size_t)ro * 64 + nt * 16 + n16] = pack;
            }
        }
#pragma unroll
        for (int off = 8; off; off >>= 1) {
            s += __shfl_xor(s, off);
            dv += __shfl_xor(dv, off);
        }
        if (n16 == 0 && ro < N_NODES) es2[ro] = make_float2(s, dv);
    }
}

// hybrid dispatch: blocks [0,NBUCK) run binB; blocks [NBUCK, NBUCK+gemm_grid)
// run layer-1 GEMM (independent work; binB hides under gemm1).
template <int K>
__global__ __launch_bounds__(256, 3) void binB_gemm_kernel(
    const unsigned* __restrict__ pairs, const int* __restrict__ cnts,
    int2* __restrict__ rowse, ushort* __restrict__ srcs,
    const void* __restrict__ A, const ushort* __restrict__ wt,
    unsigned* __restrict__ H2, const int* __restrict__ flags,
    const void* __restrict__ aS, const void* __restrict__ aD,
    float2* __restrict__ es2) {
    __shared__ short8 sB8[16 * 64];   // 16 KB (gemm blocks)
    __shared__ int s_cnt[256], s_cur[256], s_ccnt[NBA];
    if (blockIdx.x < NBUCK) {
        binB_body(pairs, cnts, rowse, srcs, blockIdx.x, threadIdx.x,
                  s_cnt, s_cur, s_ccnt);
        return;
    }
    int bid = blockIdx.x - NBUCK;
    if (flags[0]) gemm_body<K, true>(bid, A, wt, H2, flags, aS, aD, es2, sB8);
    else          gemm_body<K, false>(bid, A, wt, H2, flags, aS, aD, es2, sB8);
}

// layer-2 GEMM; block 0 also zeroes gsum/gcnt/done for the fused pool+head
// dispatch two slots later (r3-proven pattern; stream-ordered).
template <int K>
__global__ __launch_bounds__(256, 3) void gemm_mfma_kernel(
    const void* __restrict__ A, const ushort* __restrict__ wt,
    unsigned* __restrict__ H2, int a_mode, const int* __restrict__ flags,
    const void* __restrict__ aS, const void* __restrict__ aD,
    float2* __restrict__ es2, float* __restrict__ gsum, float* __restrict__ gcnt,
    int* __restrict__ done) {
    __shared__ short8 sB8[16 * 64];   // 16 frags x 1 KB = 16 KB
    if (blockIdx.x == 0) {
        for (int i = threadIdx.x; i < NGRAPH * G; i += 256) gsum[i] = 0.f;
        if (threadIdx.x < NGRAPH) gcnt[threadIdx.x] = 0.f;
        if (threadIdx.x == 0) done[0] = 0;
    }
    int af32 = (a_mode == 2) ? 0 : flags[0];   // block-uniform
    if (af32) gemm_body<K, true>(blockIdx.x, A, wt, H2, flags, aS, aD, es2, sB8);
    else      gemm_body<K, false>(blockIdx.x, A, wt, H2, flags, aS, aD, es2, sB8);
}

// Fused GAT aggregate v4: 4 waves/block, no LDS/barriers,
// 8-deep explicit gather batching, bf16 output. (v5: ushort srcs, int2 rowse)
// NOTE (r9 lesson): keep this a single plain kernel — adding POOL variants
// (runtime or co-compiled template) regressed its codegen ~4x (r3-r9).
// BYTE-IDENTICAL to the r10/r11/r12 anchor.
__global__ __launch_bounds__(256) void gat_agg_kernel(
    const unsigned* __restrict__ h2, const int2* __restrict__ rowse,
    const ushort* __restrict__ srcs, const float2* __restrict__ es2,
    const void* __restrict__ bias, ushort* __restrict__ outb,
    const int* __restrict__ flags) {
    int node = blockIdx.x * 4 + (threadIdx.x >> 6);
    if (node >= N_NODES) return;            // wave-uniform: all 64 lanes stay active
    int l = threadIdx.x & 63;
    int2 se = rowse[node];
    int start = se.x, end = se.y;
    float edd = es2[node].y;
    float m = -INFINITY, den = 0.f;
    float acc0 = 0.f, acc1 = 0.f;
    for (int c0 = start; c0 < end; c0 += 64) {
        int cn = min(end - c0, 64);
        int s = 0; float v = -INFINITY;
        if (l < cn) {
            s = (int)srcs[c0 + l];
            v = es2[s].x + edd;
            v = v >= 0.f ? v : 0.2f * v;    // LeakyReLU(0.2)
        }
        float mc = v;
#pragma unroll
        for (int off = 32; off; off >>= 1) mc = fmaxf(mc, __shfl_xor(mc, off));
        float mnew = fmaxf(m, mc);
        float scale = expf(m - mnew);        // m=-INF first chunk -> 0
        float p = (l < cn) ? expf(v - mnew) : 0.f;
        float lsum = p;
#pragma unroll
        for (int off = 32; off; off >>= 1) lsum += __shfl_xor(lsum, off);
        den = den * scale + lsum;
        acc0 *= scale; acc1 *= scale;
        int cnr = (cn + 7) & ~7;             // round up: tail lanes have p=0
        for (int i = 0; i < cnr; i += 8) {
            int sis[8]; float pis[8]; unsigned hv[8];
#pragma unroll
            for (int j = 0; j < 8; j++) {
                sis[j] = __builtin_amdgcn_readlane(s, i + j);
                pis[j] = __uint_as_float(
                    __builtin_amdgcn_readlane(__float_as_uint(p), i + j));
            }
#pragma unroll
            for (int j = 0; j < 8; j++)      // 8 outstanding 256B wave-loads
                hv[j] = h2[(size_t)sis[j] * 64 + l];
#pragma unroll
            for (int j = 0; j < 8; j++) {
                acc0 += pis[j] * bf2f((ushort)(hv[j] & 0xFFFFu));
                acc1 += pis[j] * bf2f((ushort)(hv[j] >> 16));
            }
        }
        m = mnew;
    }
    float inv = 1.f / (den + 1e-16f);
    int f32 = flags[0];
    float o0 = acc0 * inv + ldf(bias, l, f32);
    float o1 = acc1 * inv + ldf(bias, l + 64, f32);
    outb[(size_t)node * G + l]      = f2bf(selu_f(o0));
    outb[(size_t)node * G + l + 64] = f2bf(selu_f(o1));
}

// ---------------- fused pool + head v2 (last-block, latency-flat head) ----------
// Pool phase: r12 pool arithmetic verbatim. Last block (r14 lesson: v1 ran the
// 32 graphs SERIALLY with un-pipelined loads -> 381us on one block) now does:
//   A: strided independent atomic-reads of gsum[32][128] -> LDS (pipelined)
//   B: stage lw1 into LDS (strided, pipelined)
//   C: 2048 lin1 outputs striped over 128 threads, all-LDS operands
//   D: 32 threads, one graph each: lin2 + log_softmax
// Same k/j ascending summation order as r12's head -> bitwise-equal output.
__global__ void pool_head_kernel(const ushort* __restrict__ h, const void* __restrict__ batch,
                                 float* __restrict__ gsum, float* __restrict__ gcnt,
                                 int* __restrict__ done,
                                 const void* __restrict__ lw1, const void* __restrict__ lb1,
                                 const void* __restrict__ lw2, const void* __restrict__ lb2,
                                 float* __restrict__ out, const int* __restrict__ flags) {
    int t = threadIdx.x;  // 128
    int f32 = flags[0], i64 = flags[1];
    int i0 = blockIdx.x * POOL_NODES;
    int i1 = min(N_NODES, i0 + POOL_NODES);
    int cur = -1, runLen = 0;
    float acc = 0.f;
    for (int i = i0; i < i1; i++) {
        int g = min(max(ldi(batch, i, i64), 0), NGRAPH - 1);
        if (g != cur) {
            if (cur >= 0) {
                atomicAdd(&gsum[cur * G + t], acc);
                if (t == 0) atomicAdd(&gcnt[cur], (float)runLen);
            }
            cur = g; acc = 0.f; runLen = 0;
        }
        acc += bf2f(h[(size_t)i * G + t]);
        runLen++;
    }
    if (cur >= 0) {
        atomicAdd(&gsum[cur * G + t], acc);
        if (t == 0) atomicAdd(&gcnt[cur], (float)runLen);
    }

    // ---- last-block head ----
    __shared__ int isLast;
    __threadfence();                      // publish this block's atomics
    if (t == 0) isLast = (atomicAdd(done, 1) == (int)gridDim.x - 1) ? 1 : 0;
    __syncthreads();
    if (!isLast) return;

    __shared__ float zAll[NGRAPH][G];         // 16 KB
    __shared__ float w1s[G][NHID];            // 32 KB
    __shared__ float z1All[NGRAPH][NHID + 1]; // 8.125 KB (+1: kill bank-conflict col)
    __shared__ float cnts_s[NGRAPH];
    // A: counts, then pooled means (independent strided atomic reads, pipelined)
    if (t < NGRAPH) cnts_s[t] = fmaxf(atomicAdd(&gcnt[t], 0.f), 1.0f);
    __syncthreads();
    for (int i = t; i < NGRAPH * G; i += 128) {
        int g = i >> 7, c = i & (G - 1);
        zAll[g][c] = selu_f(atomicAdd(&gsum[i], 0.f) / cnts_s[g]);
    }
    // B: stage lw1 (layout k*NHID+j) into LDS
    for (int i = t; i < G * NHID; i += 128) w1s[i >> 6][i & 63] = ldf(lw1, i, f32);
    __syncthreads();
    // C: lin1 — output (g, j), striped; sum k ascending (matches r12 head order)
    for (int i = t; i < NGRAPH * NHID; i += 128) {
        int g = i >> 6, j = i & 63;
        float a = ldf(lb1, j, f32);
        for (int k = 0; k < G; k++) a += zAll[g][k] * w1s[k][j];
        z1All[g][j] = selu_f(a);
    }
    __syncthreads();
    // D: lin2 + log_softmax — one graph per thread
    if (t < NGRAPH) {
        float s0 = ldf(lb2, 0, f32), s1 = ldf(lb2, 1, f32);
        for (int j = 0; j < NHID; j++) {
            float zz = z1All[t][j];
            s0 += zz * ldf(lw2, j * 2 + 0, f32);
            s1 += zz * ldf(lw2, j * 2 + 1, f32);
        }
        float mx = fmaxf(s0, s1);
        float l = mx + logf(expf(s0 - mx) + expf(s1 - mx));
        out[t * 2 + 0] = s0 - l;
        out[t * 2 + 1] = s1 - l;
    }
}

extern "C" void kernel_launch(void* const* d_in, const int* in_sizes, int n_in,
                              void* d_out, int out_size, void* d_ws, size_t ws_size,
                              hipStream_t stream) {
    const void* x    = d_in[0];
    const void* ei   = d_in[1];
    const void* batch= d_in[2];
    const void* W1   = d_in[3];
    const void* as1  = d_in[4];
    const void* ad1  = d_in[5];
    const void* b1   = d_in[6];
    const void* W2   = d_in[7];
    const void* as2  = d_in[8];
    const void* ad2  = d_in[9];
    const void* b2   = d_in[10];
    const void* lw1  = d_in[11];
    const void* lb1  = d_in[12];
    const void* lw2  = d_in[13];
    const void* lb2  = d_in[14];
    float* out = (float*)d_out;

    char* w = (char*)d_ws;
    size_t off = 0;
    auto alloc = [&](size_t bytes) -> char* {
        char* p = w + off;
        off = (off + bytes + 255) & ~(size_t)255;
        return p;
    };
    int*      flags  = (int*)alloc(256);
    int*      done   = (int*)alloc(256);
    unsigned* h2     = (unsigned*)alloc((size_t)N_NODES * 64 * 4);  // packed bf16x2
    ushort*   abuf   = (ushort*)alloc((size_t)N_NODES * G * 2);     // bf16 activations
    float2*   es2    = (float2*)alloc((size_t)N_NODES * 8);
    int2*     rowse  = (int2*)alloc((size_t)N_NODES * 8);
    unsigned* pairs  = (unsigned*)alloc((size_t)NBUCK * NBA * CELL * 4);  // 9.8 MB
    int*      cnts   = (int*)alloc((size_t)NBUCK * NBA * 4);
    ushort*   srcs   = (ushort*)alloc((size_t)NBUCK * CAPB * 2);
    float*    gsum   = (float*)alloc((size_t)NGRAPH * G * 4);
    float*    gcnt   = (float*)alloc((size_t)NGRAPH * 4);
    ushort*   wt1    = (ushort*)alloc((size_t)IN_F * G * 2 * 2);   // hi+lo frag-ordered
    ushort*   wt2    = (ushort*)alloc((size_t)G * G * 2 * 2);

    unsigned gemm_grid = (N_NODES + 63) / 64;   // 782
    unsigned agg_grid = (N_NODES + 3) / 4;      // 12500
    unsigned pool_grid = (N_NODES + POOL_NODES - 1) / POOL_NODES;  // 782

    // 1. edge bucketing (+ inline dtype detect, flags publish, fused wt tail)
    binA_kernel<<<NBA, 256, 0, stream>>>(ei, pairs, cnts, flags, x, W1, W2, wt1, wt2);
    // 2. hybrid: binB (CSR finalize + self-loops) + layer-1 GEMM
    binB_gemm_kernel<IN_F><<<NBUCK + gemm_grid, 256, 0, stream>>>(
        pairs, cnts, rowse, srcs, x, wt1, h2, flags, as1, ad1, es2);
    // 3. layer-1 aggregate -> abuf
    gat_agg_kernel<<<agg_grid, 256, 0, stream>>>(h2, rowse, srcs, es2, b1, abuf, flags);
    // 4. layer-2 GEMM (+ gsum/gcnt/done zero by block 0)
    gemm_mfma_kernel<G><<<gemm_grid, 256, 0, stream>>>(abuf, wt2, h2, 2, flags,
                                                       as2, ad2, es2, gsum, gcnt, done);
    // 5. layer-2 aggregate
    gat_agg_kernel<<<agg_grid, 256, 0, stream>>>(h2, rowse, srcs, es2, b2, abuf, flags);
    // 6. fused pool + head (last block runs the latency-flat head)
    pool_head_kernel<<<pool_grid, 128, 0, stream>>>(abuf, batch, gsum, gcnt, done,
                                                    lw1, lb1, lw2, lb2, out, flags);
}

// Round 16
// 272.518 us; speedup vs baseline: 2.1793x; 1.3041x over previous
//
#include <hip/hip_runtime.h>
#include <hip/hip_bf16.h>
#include <math.h>

#define N_NODES 50000
#define N_EDGES 800000
#define IN_F 256
#define G 128                    // 2*HID
#define NHID 64
#define NGRAPH 32
#define NBUCK ((N_NODES + 255) / 256)    // 196 buckets (dst>>8)
#define CAPB 8192                         // srcs capacity per bucket (mean 4352+256)
#define CELL 64                           // pairs capacity per (bucket, binA-block)
#define POOL_NODES 64
#define EPB 4096                          // edges per binA block
#define NBA ((N_EDGES + EPB - 1) / EPB)   // 196 (real edges only; self-loops direct)

typedef __hip_bfloat16 bf16;
typedef unsigned short ushort;
typedef __attribute__((ext_vector_type(8))) short short8;
typedef __attribute__((ext_vector_type(4))) float f32x4;

// ---------- dtype-agnostic loads ----------
__device__ __forceinline__ float bf2f(ushort u) {
    union { unsigned u; float f; } c; c.u = ((unsigned)u) << 16; return c.f;
}
// round-to-nearest-even f32 -> bf16 (finite inputs)
__device__ __forceinline__ ushort f2bf(float f) {
    unsigned u = __float_as_uint(f);
    u += 0x7FFFu + ((u >> 16) & 1u);
    return (ushort)(u >> 16);
}
__device__ __forceinline__ float ldf(const void* p, long i, int f32) {
    return f32 ? ((const float*)p)[i] : bf2f(((const ushort*)p)[i]);
}
__device__ __forceinline__ int ldi(const void* p, long i, int i64) {
    return i64 ? (int)((const long long*)p)[i] : ((const int*)p)[i];
}

__device__ __forceinline__ float selu_f(float x) {
    const float sc = 1.0507009873554805f, al = 1.6732632423543772f;
    return x > 0.f ? sc * x : sc * al * expm1f(x);
}

// async global->LDS, 16 B/lane; lds base must be wave-uniform.
typedef const __attribute__((address_space(1))) void gas_void;
typedef __attribute__((address_space(3))) void las_void;
__device__ __forceinline__ void stage16(const void* g, void* l) {
    __builtin_amdgcn_global_load_lds((gas_void*)g, (las_void*)l, 16, 0, 0);
}

__device__ __forceinline__ void edge_sd(const void* __restrict__ ei, int e, int i64,
                                        int& s, int& d) {
    s = ldi(ei, e, i64);
    d = ldi(ei, (long)N_EDGES + e, i64);
    s = min(max(s, 0), N_NODES - 1);
    d = min(max(d, 0), N_NODES - 1);
}

// ---------------- CSR build (r4-verified): cells + direct self-loop insertion ----
// binA block k writes bucket-b records to cell (b,k), CELL=64 capacity. Only the
// 800K REAL edges stream through binA (Poisson(21)/cell -> P(>64)~1e-14); the
// 50K self-loops are inserted by binB at slot 0 of each node's range.
// cnts[b][k] fully overwritten each run -> NO pre-zeroing, NO detect dispatch:
// each binA block does its own 64-sample dtype detect; block 0 publishes flags.
// wt (weight split/frag-reorder) fused as tail: NBA*256 = 50176 >= 49152.

__global__ __launch_bounds__(256) void binA_kernel(
    const void* __restrict__ ei, unsigned* __restrict__ pairs,
    int* __restrict__ cnts, int* __restrict__ flags,
    const void* __restrict__ x,
    const void* __restrict__ W1, const void* __restrict__ W2,
    ushort* __restrict__ wt1, ushort* __restrict__ wt2) {
    __shared__ int cnt[256], lofs[256], pcur[256];
    __shared__ unsigned stage[EPB];
    __shared__ int s_i64, s_f32;
    int t = threadIdx.x;

    // ---- inline dtype detect: wave0 -> i64 flag, wave1 -> f32 flag ----
    if (t < 64) {
        const unsigned* wu = (const unsigned*)ei;
        long j = 1 + (long)t * 24986;           // odd dwords, < 1.6M (int32-safe)
        unsigned long long bal = __ballot(wu[j] != 0u);
        if (t == 0) s_i64 = (__popcll(bal) < 16) ? 1 : 0;   // i64: high words all 0
    } else if (t < 128) {
        const unsigned* xu = (const unsigned*)x;
        unsigned u = xu[(long)(t - 64) * 100000];           // < 6.4M dwords (bf16-safe)
        unsigned e = (u >> 23) & 0xFF;
        unsigned long long bal = __ballot(u == 0u || (e >= 100 && e <= 140));
        if (t == 64) s_f32 = (__popcll(bal) >= 32) ? 1 : 0;
    }
    cnt[t] = 0;
    __syncthreads();
    int i64 = s_i64, f32 = s_f32;
    if (blockIdx.x == 0 && t == 0) { flags[0] = f32; flags[1] = i64; }

    int e0 = blockIdx.x * EPB;
    int nE = min(EPB, N_EDGES - e0);
    int sj[EPB / 256], dj[EPB / 256];
#pragma unroll
    for (int j = 0; j < EPB / 256; j++) {
        int idx = j * 256 + t;
        if (idx < nE) {
            edge_sd(ei, e0 + idx, i64, sj[j], dj[j]);
            atomicAdd(&cnt[dj[j] >> 8], 1);
        } else dj[j] = -1;
    }
    __syncthreads();
    lofs[t] = cnt[t];
    for (int off = 1; off < 256; off <<= 1) {
        __syncthreads();
        int v = (t >= off) ? lofs[t - off] : 0;
        __syncthreads();
        lofs[t] += v;
    }
    __syncthreads();
    int excl = lofs[t] - cnt[t];
    __syncthreads();
    lofs[t] = excl;
    pcur[t] = excl;
    __syncthreads();
#pragma unroll
    for (int j = 0; j < EPB / 256; j++) {
        if (dj[j] >= 0) {
            int b = dj[j] >> 8;
            int lp = atomicAdd(&pcur[b], 1);
            stage[lp] = (unsigned)sj[j] | ((unsigned)(dj[j] & 255) << 16) |
                        ((unsigned)b << 24);
        }
    }
    __syncthreads();
    for (int i = t; i < nE; i += 256) {      // per-bucket contiguous cell writes
        unsigned p = stage[i];
        int b = p >> 24;
        int off2 = i - lofs[b];
        if (off2 < CELL)
            pairs[((size_t)b * NBA + blockIdx.x) * CELL + off2] = p;
    }
    if (t < NBUCK) cnts[(size_t)t * NBA + blockIdx.x] = min(cnt[t], CELL);

    // ---- fused wt tail: split-bf16 (hi+lo) frag-reorder of W1,W2 ----
    int wi = blockIdx.x * 256 + t;
    if (wi < IN_F * G + G * G) {
        const void* W; ushort* wtp; int idx;
        if (wi < IN_F * G) { W = W1; wtp = wt1; idx = wi; }
        else { W = W2; wtp = wt2; idx = wi - IN_F * G; }
        int k = idx >> 7, n = idx & (G - 1);
        float wv = ldf(W, idx, f32);
        ushort h = f2bf(wv);
        ushort lo = f2bf(wv - bf2f(h));
        int c = k >> 5, q = (k >> 3) & 3, j = k & 7;
        int nt = n >> 4, n16 = n & 15;
        int lane = q * 16 + n16;
        size_t base = ((size_t)c * 16 + nt * 2) * 512 + lane * 8 + j;
        wtp[base] = h;           // hilo = 0
        wtp[base + 512] = lo;    // hilo = 1
    }
}

// binB (r4-verified): per-bucket node counts+scan -> rowse, self-loop at slot 0,
// scatter srcs (ushort) from cells.
__device__ __forceinline__ void binB_body(
    const unsigned* __restrict__ pairs, const int* __restrict__ cnts,
    int2* __restrict__ rowse, ushort* __restrict__ srcs,
    int b, int t, int* cnt, int* cur, int* ccnt) {
    if (t < NBA) ccnt[t] = cnts[(size_t)b * NBA + t];
    int node = b * 256 + t;
    int valid = (node < N_NODES) ? 1 : 0;
    cnt[t] = valid;                        // reserve the self-loop slot
    __syncthreads();
    if (t < NBA) {                         // thread t streams cell (b,t), 4-batched
        const unsigned* cp = pairs + ((size_t)b * NBA + t) * CELL;
        int n = ccnt[t], i = 0;
        for (; i + 4 <= n; i += 4) {
            unsigned r0 = cp[i], r1 = cp[i + 1], r2 = cp[i + 2], r3 = cp[i + 3];
            atomicAdd(&cnt[(r0 >> 16) & 255], 1);
            atomicAdd(&cnt[(r1 >> 16) & 255], 1);
            atomicAdd(&cnt[(r2 >> 16) & 255], 1);
            atomicAdd(&cnt[(r3 >> 16) & 255], 1);
        }
        for (; i < n; i++) atomicAdd(&cnt[(cp[i] >> 16) & 255], 1);
    }
    __syncthreads();
    cur[t] = cnt[t];
    for (int off = 1; off < 256; off <<= 1) {
        __syncthreads();
        int v = (t >= off) ? cur[t - off] : 0;
        __syncthreads();
        cur[t] += v;
    }
    int excl = cur[t] - cnt[t];
    int base = b * CAPB;
    int myCnt = cnt[t];
    __syncthreads();
    if (valid) {
        srcs[base + excl] = (ushort)node;  // self-loop at slot 0
        rowse[node] = make_int2(base + excl, base + excl + myCnt);
    }
    cur[t] = base + excl + valid;
    __syncthreads();
    if (t < NBA) {
        const unsigned* cp = pairs + ((size_t)b * NBA + t) * CELL;
        int n = ccnt[t], i = 0;
        for (; i + 4 <= n; i += 4) {
            unsigned r0 = cp[i], r1 = cp[i + 1], r2 = cp[i + 2], r3 = cp[i + 3];
            int p0 = atomicAdd(&cur[(r0 >> 16) & 255], 1);
            int p1 = atomicAdd(&cur[(r1 >> 16) & 255], 1);
            int p2 = atomicAdd(&cur[(r2 >> 16) & 255], 1);
            int p3 = atomicAdd(&cur[(r3 >> 16) & 255], 1);
            srcs[p0] = (ushort)(r0 & 0xFFFFu);
            srcs[p1] = (ushort)(r1 & 0xFFFFu);
            srcs[p2] = (ushort)(r2 & 0xFFFFu);
            srcs[p3] = (ushort)(r3 & 0xFFFFu);
        }
        for (; i < n; i++) {
            unsigned r = cp[i];
            int p = atomicAdd(&cur[(r >> 16) & 255], 1);
            srcs[p] = (ushort)(r & 0xFFFFu);
        }
    }
}

// ---------------- GEMM: MFMA split-bf16 (hi+lo) with frag-ordered W ----------------
// Block 256 thr = 4 waves; wave = 16 rows x 128 cols.
// H2: packed bf16x2, word l = {f_l, f_{l+64}}; es2[n] = {es, ed} (float2).
template <int K, bool AF32>
__device__ __forceinline__ void gemm_body(
    int bid, const void* __restrict__ A, const ushort* __restrict__ wt,
    unsigned* __restrict__ H2, const int* __restrict__ flags,
    const void* __restrict__ aS, const void* __restrict__ aD,
    float2* __restrict__ es2, short8* sB8) {
    constexpr int NC = K / 32;
    int wave = threadIdx.x >> 6, lane = threadIdx.x & 63;
    int quad = lane >> 4, n16 = lane & 15;
    int rb = bid * 64 + wave * 16;
    int rowa = min(rb + n16, N_NODES - 1);
    f32x4 acc[8];
#pragma unroll
    for (int t = 0; t < 8; t++) acc[t] = (f32x4){0.f, 0.f, 0.f, 0.f};

    for (int c = 0; c < NC; c++) {
#pragma unroll
        for (int i = 0; i < 4; i++) {
            int fw = wave * 4 + i;
            stage16(wt + ((size_t)c * 16 + fw) * 512 + lane * 8, &sB8[fw * 64]);
        }
        float av[8];
        if (AF32) {
            const float* ap = (const float*)A + (size_t)rowa * K + c * 32 + quad * 8;
            f32x4 a0 = *(const f32x4*)ap;
            f32x4 a1 = *(const f32x4*)(ap + 4);
#pragma unroll
            for (int j = 0; j < 4; j++) { av[j] = a0[j]; av[j + 4] = a1[j]; }
        } else {
            const ushort* ap = (const ushort*)A + (size_t)rowa * K + c * 32 + quad * 8;
#pragma unroll
            for (int j = 0; j < 8; j++) av[j] = bf2f(ap[j]);
        }
        short8 ahi, alo;
#pragma unroll
        for (int j = 0; j < 8; j++) {
            ushort h = f2bf(av[j]);
            ahi[j] = (short)h;
            alo[j] = (short)f2bf(av[j] - bf2f(h));
        }
        __syncthreads();   // staging complete
#pragma unroll
        for (int nt = 0; nt < 8; nt++) {
            short8 bh = sB8[(nt * 2 + 0) * 64 + lane];
            short8 bl = sB8[(nt * 2 + 1) * 64 + lane];
            acc[nt] = __builtin_amdgcn_mfma_f32_16x16x32_bf16(ahi, bh, acc[nt], 0, 0, 0);
            acc[nt] = __builtin_amdgcn_mfma_f32_16x16x32_bf16(ahi, bl, acc[nt], 0, 0, 0);
            acc[nt] = __builtin_amdgcn_mfma_f32_16x16x32_bf16(alo, bh, acc[nt], 0, 0, 0);
        }
        __syncthreads();
    }

    // epilogue: packed-bf16 H2 store + fused ead (es2 = {h.as, h.ad})
    int f32 = flags[0];
    float asv[8], adv[8];
#pragma unroll
    for (int nt = 0; nt < 8; nt++) {
        asv[nt] = ldf(aS, nt * 16 + n16, f32);
        adv[nt] = ldf(aD, nt * 16 + n16, f32);
    }
#pragma unroll
    for (int r = 0; r < 4; r++) {
        int ro = rb + quad * 4 + r;
        float s = 0.f, dv = 0.f;
#pragma unroll
        for (int nt = 0; nt < 8; nt++) {
            s += acc[nt][r] * asv[nt];
            dv += acc[nt][r] * adv[nt];
        }
        if (ro < N_NODES) {
#pragma unroll
            for (int nt = 0; nt < 4; nt++) {   // word c = {f_c, f_{c+64}}
                unsigned pack = (unsigned)f2bf(acc[nt][r]) |
                                ((unsigned)f2bf(acc[nt + 4][r]) << 16);
                H2[(size_t)ro * 64 + nt * 16 + n16] = pack;
            }
        }
#pragma unroll
        for (int off = 8; off; off >>= 1) {
            s += __shfl_xor(s, off);
            dv += __shfl_xor(dv, off);
        }
        if (n16 == 0 && ro < N_NODES) es2[ro] = make_float2(s, dv);
    }
}

// hybrid dispatch: blocks [0,NBUCK) run binB; blocks [NBUCK, NBUCK+gemm_grid)
// run layer-1 GEMM (independent work; binB hides under gemm1).
template <int K>
__global__ __launch_bounds__(256, 3) void binB_gemm_kernel(
    const unsigned* __restrict__ pairs, const int* __restrict__ cnts,
    int2* __restrict__ rowse, ushort* __restrict__ srcs,
    const void* __restrict__ A, const ushort* __restrict__ wt,
    unsigned* __restrict__ H2, const int* __restrict__ flags,
    const void* __restrict__ aS, const void* __restrict__ aD,
    float2* __restrict__ es2) {
    __shared__ short8 sB8[16 * 64];   // 16 KB (gemm blocks)
    __shared__ int s_cnt[256], s_cur[256], s_ccnt[NBA];
    if (blockIdx.x < NBUCK) {
        binB_body(pairs, cnts, rowse, srcs, blockIdx.x, threadIdx.x,
                  s_cnt, s_cur, s_ccnt);
        return;
    }
    int bid = blockIdx.x - NBUCK;
    if (flags[0]) gemm_body<K, true>(bid, A, wt, H2, flags, aS, aD, es2, sB8);
    else          gemm_body<K, false>(bid, A, wt, H2, flags, aS, aD, es2, sB8);
}

// layer-2 GEMM; block 0 also zeroes gsum/gcnt for the pool dispatch two slots
// later (r3-proven pattern; stream-ordered).
template <int K>
__global__ __launch_bounds__(256, 3) void gemm_mfma_kernel(
    const void* __restrict__ A, const ushort* __restrict__ wt,
    unsigned* __restrict__ H2, int a_mode, const int* __restrict__ flags,
    const void* __restrict__ aS, const void* __restrict__ aD,
    float2* __restrict__ es2, float* __restrict__ gsum, float* __restrict__ gcnt) {
    __shared__ short8 sB8[16 * 64];   // 16 frags x 1 KB = 16 KB
    if (blockIdx.x == 0) {
        for (int i = threadIdx.x; i < NGRAPH * G; i += 256) gsum[i] = 0.f;
        if (threadIdx.x < NGRAPH) gcnt[threadIdx.x] = 0.f;
    }
    int af32 = (a_mode == 2) ? 0 : flags[0];   // block-uniform
    if (af32) gemm_body<K, true>(blockIdx.x, A, wt, H2, flags, aS, aD, es2, sB8);
    else      gemm_body<K, false>(blockIdx.x, A, wt, H2, flags, aS, aD, es2, sB8);
}

// Fused GAT aggregate v4: 4 waves/block, no LDS/barriers,
// 8-deep explicit gather batching, bf16 output. (v5: ushort srcs, int2 rowse)
// NOTE (r9 lesson): keep this a single plain kernel — adding POOL variants
// (runtime or co-compiled template) regressed its codegen ~4x (r3-r9).
// BYTE-IDENTICAL to the r10/r11/r12 anchor.
__global__ __launch_bounds__(256) void gat_agg_kernel(
    const unsigned* __restrict__ h2, const int2* __restrict__ rowse,
    const ushort* __restrict__ srcs, const float2* __restrict__ es2,
    const void* __restrict__ bias, ushort* __restrict__ outb,
    const int* __restrict__ flags) {
    int node = blockIdx.x * 4 + (threadIdx.x >> 6);
    if (node >= N_NODES) return;            // wave-uniform: all 64 lanes stay active
    int l = threadIdx.x & 63;
    int2 se = rowse[node];
    int start = se.x, end = se.y;
    float edd = es2[node].y;
    float m = -INFINITY, den = 0.f;
    float acc0 = 0.f, acc1 = 0.f;
    for (int c0 = start; c0 < end; c0 += 64) {
        int cn = min(end - c0, 64);
        int s = 0; float v = -INFINITY;
        if (l < cn) {
            s = (int)srcs[c0 + l];
            v = es2[s].x + edd;
            v = v >= 0.f ? v : 0.2f * v;    // LeakyReLU(0.2)
        }
        float mc = v;
#pragma unroll
        for (int off = 32; off; off >>= 1) mc = fmaxf(mc, __shfl_xor(mc, off));
        float mnew = fmaxf(m, mc);
        float scale = expf(m - mnew);        // m=-INF first chunk -> 0
        float p = (l < cn) ? expf(v - mnew) : 0.f;
        float lsum = p;
#pragma unroll
        for (int off = 32; off; off >>= 1) lsum += __shfl_xor(lsum, off);
        den = den * scale + lsum;
        acc0 *= scale; acc1 *= scale;
        int cnr = (cn + 7) & ~7;             // round up: tail lanes have p=0
        for (int i = 0; i < cnr; i += 8) {
            int sis[8]; float pis[8]; unsigned hv[8];
#pragma unroll
            for (int j = 0; j < 8; j++) {
                sis[j] = __builtin_amdgcn_readlane(s, i + j);
                pis[j] = __uint_as_float(
                    __builtin_amdgcn_readlane(__float_as_uint(p), i + j));
            }
#pragma unroll
            for (int j = 0; j < 8; j++)      // 8 outstanding 256B wave-loads
                hv[j] = h2[(size_t)sis[j] * 64 + l];
#pragma unroll
            for (int j = 0; j < 8; j++) {
                acc0 += pis[j] * bf2f((ushort)(hv[j] & 0xFFFFu));
                acc1 += pis[j] * bf2f((ushort)(hv[j] >> 16));
            }
        }
        m = mnew;
    }
    float inv = 1.f / (den + 1e-16f);
    int f32 = flags[0];
    float o0 = acc0 * inv + ldf(bias, l, f32);
    float o1 = acc1 * inv + ldf(bias, l + 64, f32);
    outb[(size_t)node * G + l]      = f2bf(selu_f(o0));
    outb[(size_t)node * G + l + 64] = f2bf(selu_f(o1));
}

// ---------------- pool (+fused count) + head ----------------
__global__ void pool_kernel(const ushort* __restrict__ h, const void* __restrict__ batch,
                            float* __restrict__ gsum, float* __restrict__ gcnt,
                            const int* __restrict__ flags) {
    int t = threadIdx.x;  // 128
    int i64 = flags[1];
    int i0 = blockIdx.x * POOL_NODES;
    int i1 = min(N_NODES, i0 + POOL_NODES);
    int cur = -1, runLen = 0;
    float acc = 0.f;
    for (int i = i0; i < i1; i++) {
        int g = min(max(ldi(batch, i, i64), 0), NGRAPH - 1);
        if (g != cur) {
            if (cur >= 0) {
                atomicAdd(&gsum[cur * G + t], acc);
                if (t == 0) atomicAdd(&gcnt[cur], (float)runLen);
            }
            cur = g; acc = 0.f; runLen = 0;
        }
        acc += bf2f(h[(size_t)i * G + t]);
        runLen++;
    }
    if (cur >= 0) {
        atomicAdd(&gsum[cur * G + t], acc);
        if (t == 0) atomicAdd(&gcnt[cur], (float)runLen);
    }
}

// pooled -> selu -> lin1+selu -> lin2 -> log_softmax; OUTPUT FLOAT32
__global__ void head_kernel(const float* __restrict__ gsum, const float* __restrict__ gcnt,
                            const void* __restrict__ lw1, const void* __restrict__ lb1,
                            const void* __restrict__ lw2, const void* __restrict__ lb2,
                            float* __restrict__ out, const int* __restrict__ flags) {
    int g = blockIdx.x, t = threadIdx.x;  // 64
    int f32 = flags[0];
    __shared__ float z[G];
    __shared__ float z1[NHID];
    __shared__ float z2[2];
    float cnt = fmaxf(gcnt[g], 1.0f);
    z[t]      = selu_f(gsum[g * G + t] / cnt);
    z[t + 64] = selu_f(gsum[g * G + 64 + t] / cnt);
    __syncthreads();
    float a = ldf(lb1, t, f32);
    for (int k = 0; k < G; k++) a += z[k] * ldf(lw1, k * NHID + t, f32);
    z1[t] = selu_f(a);
    __syncthreads();
    if (t < 2) {
        float s = ldf(lb2, t, f32);
        for (int j = 0; j < NHID; j++) s += z1[j] * ldf(lw2, j * 2 + t, f32);
        z2[t] = s;
    }
    __syncthreads();
    if (t == 0) {
        float mx = fmaxf(z2[0], z2[1]);
        float l = mx + logf(expf(z2[0] - mx) + expf(z2[1] - mx));
        out[g * 2 + 0] = z2[0] - l;
        out[g * 2 + 1] = z2[1] - l;
    }
}

extern "C" void kernel_launch(void* const* d_in, const int* in_sizes, int n_in,
                              void* d_out, int out_size, void* d_ws, size_t ws_size,
                              hipStream_t stream) {
    const void* x    = d_in[0];
    const void* ei   = d_in[1];
    const void* batch= d_in[2];
    const void* W1   = d_in[3];
    const void* as1  = d_in[4];
    const void* ad1  = d_in[5];
    const void* b1   = d_in[6];
    const void* W2   = d_in[7];
    const void* as2  = d_in[8];
    const void* ad2  = d_in[9];
    const void* b2   = d_in[10];
    const void* lw1  = d_in[11];
    const void* lb1  = d_in[12];
    const void* lw2  = d_in[13];
    const void* lb2  = d_in[14];
    float* out = (float*)d_out;

    char* w = (char*)d_ws;
    size_t off = 0;
    auto alloc = [&](size_t bytes) -> char* {
        char* p = w + off;
        off = (off + bytes + 255) & ~(size_t)255;
        return p;
    };
    int*      flags  = (int*)alloc(256);
    unsigned* h2     = (unsigned*)alloc((size_t)N_NODES * 64 * 4);  // packed bf16x2
    ushort*   abuf   = (ushort*)alloc((size_t)N_NODES * G * 2);     // bf16 activations
    float2*   es2    = (float2*)alloc((size_t)N_NODES * 8);
    int2*     rowse  = (int2*)alloc((size_t)N_NODES * 8);
    unsigned* pairs  = (unsigned*)alloc((size_t)NBUCK * NBA * CELL * 4);  // 9.8 MB
    int*      cnts   = (int*)alloc((size_t)NBUCK * NBA * 4);
    ushort*   srcs   = (ushort*)alloc((size_t)NBUCK * CAPB * 2);
    float*    gsum   = (float*)alloc((size_t)NGRAPH * G * 4);
    float*    gcnt   = (float*)alloc((size_t)NGRAPH * 4);
    ushort*   wt1    = (ushort*)alloc((size_t)IN_F * G * 2 * 2);   // hi+lo frag-ordered
    ushort*   wt2    = (ushort*)alloc((size_t)G * G * 2 * 2);

    unsigned gemm_grid = (N_NODES + 63) / 64;   // 782
    unsigned agg_grid = (N_NODES + 3) / 4;      // 12500

    // 1. edge bucketing (+ inline dtype detect, flags publish, fused wt tail)
    binA_kernel<<<NBA, 256, 0, stream>>>(ei, pairs, cnts, flags, x, W1, W2, wt1, wt2);
    // 2. hybrid: binB (CSR finalize + self-loops) + layer-1 GEMM
    binB_gemm_kernel<IN_F><<<NBUCK + gemm_grid, 256, 0, stream>>>(
        pairs, cnts, rowse, srcs, x, wt1, h2, flags, as1, ad1, es2);
    // 3. layer-1 aggregate -> abuf
    gat_agg_kernel<<<agg_grid, 256, 0, stream>>>(h2, rowse, srcs, es2, b1, abuf, flags);
    // 4. layer-2 GEMM (+ gsum/gcnt zero by block 0)
    gemm_mfma_kernel<G><<<gemm_grid, 256, 0, stream>>>(abuf, wt2, h2, 2, flags,
                                                       as2, ad2, es2, gsum, gcnt);
    // 5. layer-2 aggregate
    gat_agg_kernel<<<agg_grid, 256, 0, stream>>>(h2, rowse, srcs, es2, b2, abuf, flags);
    // 6. pool (+count) + 7. head
    pool_kernel<<<(N_NODES + POOL_NODES - 1) / POOL_NODES, 128, 0, stream>>>(
        abuf, batch, gsum, gcnt, flags);
    head_kernel<<<NGRAPH, 64, 0, stream>>>(gsum, gcnt, lw1, lb1, lw2, lb2, out, flags);
}